// Round 1
// baseline (368.077 us; speedup 1.0000x reference)
//
#include <hip/hip_runtime.h>

// FP32 bit-pulse -> FP8 E4M3 bit-pulse converter.
// One thread per value: 8x float4 loads (128 B contiguous per lane, all bytes
// consumed), integer RNE rounding logic, 2x float4 stores.

__global__ __launch_bounds__(256) void fp8cvt_kernel(const float4* __restrict__ in,
                                                     float4* __restrict__ out,
                                                     int n) {
    int i = blockIdx.x * blockDim.x + threadIdx.x;
    if (i >= n) return;

    const float4* p = in + (size_t)i * 8;

    // Assemble the 32-bit word, MSB first: [S, E7..E0, M22..M0]
    unsigned word = 0u;
#pragma unroll
    for (int k = 0; k < 8; ++k) {
        float4 v = p[k];
        unsigned b0 = (v.x != 0.0f);
        unsigned b1 = (v.y != 0.0f);
        unsigned b2 = (v.z != 0.0f);
        unsigned b3 = (v.w != 0.0f);
        word = (word << 4) | (b0 << 3) | (b1 << 2) | (b2 << 1) | b3;
    }

    unsigned s    = word >> 31;
    int      exp  = (int)((word >> 23) & 0xFF);
    unsigned mant = word & 0x7FFFFFu;

    // ---- normal path: exp8 = exp - 120, RNE 23 -> 3 mantissa bits ----
    unsigned kept  = mant >> 20;
    unsigned R     = (mant >> 19) & 1u;
    unsigned S     = (mant & ((1u << 19) - 1u)) != 0u;
    unsigned L     = kept & 1u;
    unsigned mr    = kept + (R & (S | L));
    unsigned carry = mr >> 3;
    unsigned mant_norm = carry ? 0u : (mr & 7u);
    int      exp_norm  = exp - 120 + (int)carry;

    // ---- subnormal path (117 <= exp <= 120) ----
    unsigned full = (1u << 23) | mant;
    int sh = 141 - exp;
    sh = sh < 1 ? 1 : (sh > 24 ? 24 : sh);
    unsigned kept_s = full >> sh;
    unsigned Rs = (full >> (sh - 1)) & 1u;
    unsigned Ss = (full & ((1u << (sh - 1)) - 1u)) != 0u;
    unsigned Ls = kept_s & 1u;
    unsigned ms = kept_s + (Rs & (Ss | Ls));
    unsigned sub_of   = (ms >= 8u);
    unsigned sub_exp  = sub_of ? 1u : 0u;
    unsigned sub_mant = sub_of ? 0u : ms;

    // ---- select overflow / subnormal / underflow / normal ----
    int exp8, mant8;
    if (exp > 134)                      { exp8 = 15;            mant8 = 6; }
    else if (exp >= 117 && exp <= 120)  { exp8 = (int)sub_exp;  mant8 = (int)sub_mant; }
    else if (exp < 117)                 { exp8 = 0;             mant8 = 0; }
    else                                { exp8 = exp_norm;      mant8 = (int)mant_norm; }

    float4 o0, o1;
    o0.x = (float)s;
    o0.y = (float)((exp8 >> 3) & 1);
    o0.z = (float)((exp8 >> 2) & 1);
    o0.w = (float)((exp8 >> 1) & 1);
    o1.x = (float)(exp8 & 1);
    o1.y = (float)((mant8 >> 2) & 1);
    o1.z = (float)((mant8 >> 1) & 1);
    o1.w = (float)(mant8 & 1);

    out[(size_t)i * 2]     = o0;
    out[(size_t)i * 2 + 1] = o1;
}

extern "C" void kernel_launch(void* const* d_in, const int* in_sizes, int n_in,
                              void* d_out, int out_size, void* d_ws, size_t ws_size,
                              hipStream_t stream) {
    const float4* in  = (const float4*)d_in[0];
    float4*       out = (float4*)d_out;
    int n = in_sizes[0] / 32;   // number of FP32 values
    int block = 256;
    int grid  = (n + block - 1) / block;
    fp8cvt_kernel<<<grid, block, 0, stream>>>(in, out, n);
}